// Round 4
// baseline (6330.762 us; speedup 1.0000x reference)
//
#include <hip/hip_runtime.h>

// ---------------- problem dims (fixed by reference) ----------------
#define T_   3
#define B_   16
#define D_   512
#define HW_  484
#define M_   1452          // T_*HW_
#define K_   128
#define TEMP_ 30.0f
#define EPS_  1e-5f
// NORM_SCALE = sqrt(1/(512*4*4)); inorm scale = NORM_SCALE*sqrt(D*HW/(ss+eps))
#define NORM_SCALE_ ((float)0.011048543456039806)

// ---------------- block-reduce helpers (blockDim == 256) ----------------
__device__ __forceinline__ float blockReduceSum256(float v) {
  __shared__ float red[4];
  #pragma unroll
  for (int o = 32; o > 0; o >>= 1) v += __shfl_xor(v, o);
  if ((threadIdx.x & 63) == 0) red[threadIdx.x >> 6] = v;
  __syncthreads();
  float t = red[0] + red[1] + red[2] + red[3];
  __syncthreads();
  return t;
}

__device__ __forceinline__ float blockReduceMax256(float v) {
  __shared__ float redm[4];
  #pragma unroll
  for (int o = 32; o > 0; o >>= 1) v = fmaxf(v, __shfl_xor(v, o));
  if ((threadIdx.x & 63) == 0) redm[threadIdx.x >> 6] = v;
  __syncthreads();
  float t = fmaxf(fmaxf(redm[0], redm[1]), fmaxf(redm[2], redm[3]));
  __syncthreads();
  return t;
}

// ---------------- softmax(qxm) -> wts[3] ----------------
__global__ void k_wts(const float* __restrict__ qxm, float* __restrict__ wts) {
  if (threadIdx.x == 0 && blockIdx.x == 0) {
    float a = qxm[0], b = qxm[1], c = qxm[2];
    float m = fmaxf(a, fmaxf(b, c));
    float ea = __expf(a - m), eb = __expf(b - m), ec = __expf(c - m);
    float s = ea + eb + ec;
    wts[0] = ea / s; wts[1] = eb / s; wts[2] = ec / s;
  }
}

// ---------------- feat [TB, D, HW] -> X [t*HW+hw, b, d] ----------------
__global__ __launch_bounds__(256) void k_transpose_in(
    const float* __restrict__ in, float* __restrict__ out) {
  __shared__ float tile[32][33];
  const int tb = blockIdx.z;           // t*B_+b
  const int t = tb / B_, b = tb % B_;
  const int hw0 = blockIdx.x * 32, d0 = blockIdx.y * 32;
  const int tx = threadIdx.x & 31, ty = threadIdx.x >> 5;   // 32x8
  for (int i = ty; i < 32; i += 8) {
    int d = d0 + i, hw = hw0 + tx;
    tile[i][tx] = (hw < HW_) ? in[((long)tb*D_ + d)*HW_ + hw] : 0.f;
  }
  __syncthreads();
  for (int i = ty; i < 32; i += 8) {
    int hw = hw0 + i, d = d0 + tx;
    if (hw < HW_) out[(((long)t*HW_ + hw)*B_ + b)*D_ + d] = tile[tx][i];
  }
}

// ---------------- outImg [hw,b,d] -> out [b, d, hw] (per image) ----------------
__global__ __launch_bounds__(256) void k_out_store(
    const float* __restrict__ Xo, float* __restrict__ outP) {
  __shared__ float tile[32][33];
  const int b = blockIdx.z;
  const int hw0 = blockIdx.x * 32, d0 = blockIdx.y * 32;
  const int tx = threadIdx.x & 31, ty = threadIdx.x >> 5;
  for (int i = ty; i < 32; i += 8) {
    int hw = hw0 + i, d = d0 + tx;
    tile[i][tx] = (hw < HW_) ? Xo[((long)hw*B_ + b)*D_ + d] : 0.f;
  }
  __syncthreads();
  for (int i = ty; i < 32; i += 8) {
    int d = d0 + i, hw = hw0 + tx;
    if (hw < HW_) outP[((long)b*D_ + d)*HW_ + hw] = tile[tx][i];
  }
}

// ---------------- Y[l,b,:] = l2norm(X[l,b,:] @ W^T + bias), K=128, D=512 ----------
// 32 rows x 128 cols per WG; thread: 2 rows x 8 cols (k = kg+16*i)
__global__ __launch_bounds__(256) void k_proj_l2n(
    const float* __restrict__ X, const float* __restrict__ Wm,
    const float* __restrict__ bias, float* __restrict__ Y, int nRows) {
  __shared__ __align__(16) float sX[32][68];
  __shared__ __align__(16) float sW[128][68];
  const int tid = threadIdx.x;
  const int rp = tid >> 4;        // 0..15 row-pair
  const int kg = tid & 15;        // 0..15
  const int row0 = blockIdx.x * 32;
  float acc[2][8] = {};
  for (int dc = 0; dc < D_; dc += 64) {
    for (int f = tid; f < 32*16; f += 256) {
      int rr = f >> 4, c4 = (f & 15) * 4;
      int rg = row0 + rr;
      float4 v = make_float4(0.f, 0.f, 0.f, 0.f);
      if (rg < nRows) v = *(const float4*)&X[(long)rg*D_ + dc + c4];
      *(float4*)&sX[rr][c4] = v;
    }
    for (int f = tid; f < 128*16; f += 256) {
      int rr = f >> 4, c4 = (f & 15) * 4;
      *(float4*)&sW[rr][c4] = *(const float4*)&Wm[rr*D_ + dc + c4];
    }
    __syncthreads();
    #pragma unroll
    for (int d4 = 0; d4 < 64; d4 += 4) {
      float4 xa = *(const float4*)&sX[rp*2+0][d4];
      float4 xb = *(const float4*)&sX[rp*2+1][d4];
      #pragma unroll
      for (int i = 0; i < 8; i++) {
        float4 w = *(const float4*)&sW[kg + 16*i][d4];
        acc[0][i] += xa.x*w.x + xa.y*w.y + xa.z*w.z + xa.w*w.w;
        acc[1][i] += xb.x*w.x + xb.y*w.y + xb.z*w.z + xb.w*w.w;
      }
    }
    __syncthreads();
  }
  #pragma unroll
  for (int r = 0; r < 2; r++) {
    float ss = 0.f;
    #pragma unroll
    for (int i = 0; i < 8; i++) {
      acc[r][i] += bias[kg + 16*i];
      ss += acc[r][i] * acc[r][i];
    }
    ss += __shfl_xor(ss, 1); ss += __shfl_xor(ss, 2);
    ss += __shfl_xor(ss, 4); ss += __shfl_xor(ss, 8);
    float inv = 1.f / fmaxf(sqrtf(ss), 1e-12f);
    int rg = row0 + rp*2 + r;
    if (rg < nRows) {
      #pragma unroll
      for (int i = 0; i < 8; i++)
        Y[(long)rg*K_ + kg + 16*i] = acc[r][i] * inv;
    }
  }
}

// ------------- S[b,q,j] = TEMP * sum_e Q[q,b,e]*Kt[j,b,e] --------------------
// Tile: 128(q) x NJ*16(j); e staged in chunks of 32. Thread: 8 x NJ outputs.
template<int NJ>
__global__ __launch_bounds__(256) void k_scores(
    const float* __restrict__ Q, const float* __restrict__ Kt,
    float* __restrict__ S, int Lq, int Lk) {
  __shared__ __align__(16) float sQ[128][36];
  __shared__ __align__(16) float sK[NJ*16][36];
  const int b = blockIdx.z;
  const int q0 = blockIdx.x * 128;
  const int j0 = blockIdx.y * (NJ*16);
  const int tid = threadIdx.x;
  const int tx = tid & 15, ty = tid >> 4;
  float acc[8][NJ] = {};
  for (int ec = 0; ec < K_; ec += 32) {
    for (int f = tid; f < 128*8; f += 256) {
      int rr = f >> 3, c4 = (f & 7) * 4;
      int qg = q0 + rr;
      float4 v = make_float4(0.f, 0.f, 0.f, 0.f);
      if (qg < Lq) v = *(const float4*)&Q[((long)qg*B_ + b)*K_ + ec + c4];
      *(float4*)&sQ[rr][c4] = v;
    }
    for (int f = tid; f < NJ*16*8; f += 256) {
      int rr = f >> 3, c4 = (f & 7) * 4;
      int jg = j0 + rr;
      float4 v = make_float4(0.f, 0.f, 0.f, 0.f);
      if (jg < Lk) v = *(const float4*)&Kt[((long)jg*B_ + b)*K_ + ec + c4];
      *(float4*)&sK[rr][c4] = v;
    }
    __syncthreads();
    #pragma unroll
    for (int e4 = 0; e4 < 32; e4 += 4) {
      float4 qa[8]; float4 kb[NJ];
      #pragma unroll
      for (int i = 0; i < 8; i++) qa[i] = *(const float4*)&sQ[ty + 16*i][e4];
      #pragma unroll
      for (int j = 0; j < NJ; j++) kb[j] = *(const float4*)&sK[tx + 16*j][e4];
      #pragma unroll
      for (int i = 0; i < 8; i++)
        #pragma unroll
        for (int j = 0; j < NJ; j++)
          acc[i][j] += qa[i].x*kb[j].x + qa[i].y*kb[j].y
                     + qa[i].z*kb[j].z + qa[i].w*kb[j].w;
    }
    __syncthreads();
  }
  #pragma unroll
  for (int i = 0; i < 8; i++) {
    int qg = q0 + ty + 16*i;
    if (qg >= Lq) continue;
    float* row = S + ((long)b*Lq + qg)*Lk;
    #pragma unroll
    for (int j = 0; j < NJ; j++) {
      int jg = j0 + tx + 16*j;
      if (jg < Lk) row[jg] = TEMP_ * acc[i][j];
    }
  }
}

// ---------------- row softmax in place; len % 4 == 0, len <= 1452 ----------------
__global__ __launch_bounds__(256) void k_softmax(float* __restrict__ S, int len) {
  __shared__ __align__(16) float buf[1456];
  const long row = blockIdx.x;
  float* p = S + row * (long)len;
  const int tid = threadIdx.x;
  float mx = -1e30f;
  for (int i = tid*4; i < len; i += 1024) {
    float4 v = *(const float4*)&p[i];
    *(float4*)&buf[i] = v;
    mx = fmaxf(mx, fmaxf(fmaxf(v.x, v.y), fmaxf(v.z, v.w)));
  }
  mx = blockReduceMax256(mx);
  float sum = 0.f;
  for (int i = tid*4; i < len; i += 1024) {
    float4 v = *(float4*)&buf[i];
    v.x = __expf(v.x - mx); v.y = __expf(v.y - mx);
    v.z = __expf(v.z - mx); v.w = __expf(v.w - mx);
    sum += v.x + v.y + v.z + v.w;
    *(float4*)&buf[i] = v;
  }
  sum = blockReduceSum256(sum);
  float inv = 1.f / sum;
  for (int i = tid*4; i < len; i += 1024) {
    float4 v = *(float4*)&buf[i];
    v.x *= inv; v.y *= inv; v.z *= inv; v.w *= inv;
    *(float4*)&p[i] = v;
  }
}

// --------- dst[q,b,:] = sum_k S[b,q,k]*(scale_k)*V[k,b,:] (+ R[q,b,:]) ----------
// Tile: 128(q) x NJ*16(d); k staged in chunks of 32. SCALE: per-k pos1 from label.
template<int NJ, bool RES, bool SCALE>
__global__ __launch_bounds__(256) void k_av(
    const float* __restrict__ S, const float* __restrict__ V,
    const float* __restrict__ R, const float* __restrict__ label,
    float* __restrict__ dst, int Lq, int Lk) {
  __shared__ __align__(16) float sS[128][36];
  __shared__ __align__(16) float sV[32][NJ*16 + 4];
  const int b = blockIdx.z;
  const int q0 = blockIdx.x * 128;
  const int d0 = blockIdx.y * (NJ*16);
  const int tid = threadIdx.x;
  const int tx = tid & 15, ty = tid >> 4;
  float acc[8][NJ] = {};
  for (int k0 = 0; k0 < Lk; k0 += 32) {
    for (int f = tid; f < 128*8; f += 256) {
      int rr = f >> 3, c4 = (f & 7) * 4;
      int qg = q0 + rr;
      int kk = k0 + c4;
      float4 v = make_float4(0.f, 0.f, 0.f, 0.f);
      if (qg < Lq && kk < Lk) v = *(const float4*)&S[((long)b*Lq + qg)*Lk + kk];
      if (SCALE) {
        float* pv = (float*)&v;
        #pragma unroll
        for (int u = 0; u < 4; u++) {
          int kj = kk + u;
          float pl = 0.f;
          if (kj < Lk) {
            int pp = kj / HW_, hh = kj - pp*HW_;
            pl = label[(pp*B_ + b)*HW_ + hh];   // pos1[j,b]
          }
          pv[u] *= pl;
        }
      }
      *(float4*)&sS[rr][c4] = v;
    }
    for (int f = tid; f < 32*NJ*4; f += 256) {
      int kk = f / (NJ*4), c4 = (f % (NJ*4)) * 4;
      int kg = k0 + kk;
      float4 v = make_float4(0.f, 0.f, 0.f, 0.f);
      if (kg < Lk) v = *(const float4*)&V[((long)kg*B_ + b)*D_ + d0 + c4];
      *(float4*)&sV[kk][c4] = v;
    }
    __syncthreads();
    #pragma unroll
    for (int k4 = 0; k4 < 32; k4 += 4) {
      float4 qa[8];
      #pragma unroll
      for (int i = 0; i < 8; i++) qa[i] = *(const float4*)&sS[ty + 16*i][k4];
      #pragma unroll
      for (int u = 0; u < 4; u++) {
        float vb[NJ];
        #pragma unroll
        for (int j = 0; j < NJ; j++) vb[j] = sV[k4 + u][tx + 16*j];
        #pragma unroll
        for (int i = 0; i < 8; i++) {
          float qv = (u == 0) ? qa[i].x : (u == 1) ? qa[i].y
                   : (u == 2) ? qa[i].z : qa[i].w;
          #pragma unroll
          for (int j = 0; j < NJ; j++) acc[i][j] += qv * vb[j];
        }
      }
    }
    __syncthreads();
  }
  #pragma unroll
  for (int i = 0; i < 8; i++) {
    int qg = q0 + ty + 16*i;
    if (qg >= Lq) continue;
    long off = ((long)qg*B_ + b)*D_ + d0;
    #pragma unroll
    for (int j = 0; j < NJ; j++) {
      int dg = tx + 16*j;
      float o = acc[i][j];
      if (RES) o += R[off + dg];
      dst[off + dg] = o;
    }
  }
}

// ------- W2[b,q,k] = sum_p SC[b,q,p*HW+k]*label[p,b,k]  (k in [0,HW)) -------
__global__ __launch_bounds__(256) void k_w2(
    const float* __restrict__ SC, const float* __restrict__ label,
    float* __restrict__ W2) {
  long idx = (long)blockIdx.x*256 + threadIdx.x;
  if (idx >= (long)B_*HW_*HW_) return;
  int k = (int)(idx % HW_);
  long t = idx / HW_;
  int q = (int)(t % HW_);
  int b = (int)(t / HW_);
  const float* srow = SC + ((long)b*HW_ + q)*M_;
  float s = 0.f;
  #pragma unroll
  for (int p = 0; p < T_; p++)
    s += srow[p*HW_ + k] * label[(p*B_ + b)*HW_ + k];
  W2[idx] = s;
}

// ------- mask[q,b] = sum_k W2[b,q,k]  (== sum_j aff*pos1) -------
__global__ __launch_bounds__(256) void k_mask(
    const float* __restrict__ W2, float* __restrict__ maskB) {
  const int row = blockIdx.x;          // b*HW_+q
  const int b = row / HW_, q = row % HW_;
  const float* p = W2 + (long)row*HW_;
  float s = 0.f;
  for (int i = threadIdx.x; i < HW_; i += 256) s += p[i];
  s = blockReduceSum256(s);
  if (threadIdx.x == 0) maskB[q*B_ + b] = s;
}

// ------- inorm pass 1: partial sums of squares per (g,b), 16 chunks -------
template<bool WM>
__global__ __launch_bounds__(256) void k_ss_partial(
    const float* __restrict__ X, const float* __restrict__ maskB,
    float* __restrict__ part) {
  const int gb = blockIdx.x;           // g*B_+b
  const int c = blockIdx.y;            // 0..15
  const int g = gb / B_, b = gb % B_;
  const float4* Xp = (const float4*)X;
  const int CH = (HW_*D_/4) / 16;      // 3872 float4 per chunk
  float s = 0.f;
  for (int i = c*CH + threadIdx.x; i < (c+1)*CH; i += 256) {
    int hw = i >> 7;                   // i / (D_/4)
    int d4 = i & 127;
    float4 v = Xp[(((long)g*HW_ + hw)*B_ + b)*(D_/4) + d4];
    float m = 1.f;
    if (WM) m = maskB[hw*B_ + b];
    float a = v.x*m, e = v.y*m, f = v.z*m, h = v.w*m;
    s += a*a + e*e + f*f + h*h;
  }
  s = blockReduceSum256(s);
  if (threadIdx.x == 0) part[gb*16 + c] = s;
}

// ------- inorm pass 2: scale factor per group -------
__global__ void k_ss_final(const float* __restrict__ part,
                           float* __restrict__ scaleG, int nG) {
  int g = threadIdx.x;
  if (g < nG) {
    float s = 0.f;
    #pragma unroll
    for (int c = 0; c < 16; c++) s += part[g*16 + c];
    scaleG[g] = NORM_SCALE_ * sqrtf((float)(D_*HW_) / (s + EPS_));
  }
}

// ------- x *= scaleG[g*B+b], x is [G*HW, B, D] viewed as float4 -------
__global__ __launch_bounds__(256) void k_inorm_apply(
    float* __restrict__ X, const float* __restrict__ scaleG, long n4) {
  long i = (long)blockIdx.x*256 + threadIdx.x;
  if (i >= n4) return;
  long t = i >> 7;                     // / (D_/4)
  int b = (int)(t & 15);
  long l = t >> 4;
  int g = (int)(l / HW_);
  float sc = scaleG[g*B_ + b];
  float4* Xp = (float4*)X;
  float4 v = Xp[i];
  v.x *= sc; v.y *= sc; v.z *= sc; v.w *= sc;
  Xp[i] = v;
}

// ------- outImg (+)= wts[widx]*scale[b]*(X or tgt*mask) -------
template<int MODE>   // 0: overwrite with tgt*mask ; 1: add X
__global__ __launch_bounds__(256) void k_accum(
    const float* __restrict__ X, const float* __restrict__ maskB,
    const float* __restrict__ scaleG, const float* __restrict__ wts,
    float* __restrict__ outI, int widx) {
  long i = (long)blockIdx.x*256 + threadIdx.x;
  const long n4 = (long)HW_*B_*D_/4;
  if (i >= n4) return;
  long t = i >> 7;
  int b = (int)(t & 15);
  int hw = (int)(t >> 4);
  float w = wts[widx] * scaleG[b];
  if (MODE == 0) w *= maskB[hw*B_ + b];
  const float4* Xp = (const float4*)X;
  float4 v = Xp[i];
  float4* Op = (float4*)outI;
  if (MODE == 0) {
    float4 o; o.x = v.x*w; o.y = v.y*w; o.z = v.z*w; o.w = v.w*w;
    Op[i] = o;
  } else {
    float4 o = Op[i];
    o.x += v.x*w; o.y += v.y*w; o.z += v.z*w; o.w += v.w*w;
    Op[i] = o;
  }
}

// =======================================================================
extern "C" void kernel_launch(void* const* d_in, const int* in_sizes, int n_in,
                              void* d_out, int out_size, void* d_ws, size_t ws_size,
                              hipStream_t stream) {
  (void)in_sizes; (void)n_in; (void)out_size; (void)ws_size;
  const float* train_feat = (const float*)d_in[0];
  const float* test_feat  = (const float*)d_in[1];
  const float* label      = (const float*)d_in[2];
  const float* sw  = (const float*)d_in[3];
  const float* sb  = (const float*)d_in[4];
  const float* cw  = (const float*)d_in[5];
  const float* cb  = (const float*)d_in[6];
  const float* qxm = (const float*)d_in[7];
  float* out = (float*)d_out;

  // ---- workspace layout (floats); total ~75.4M floats ~ 302 MB ----
  float* ws = (float*)d_ws;
  long o = 0;
  float* srcT  = ws + o; o += (long)M_*B_*D_;     // [M,B,D] transposed train
  float* tstT  = ws + o; o += (long)M_*B_*D_;     // [M,B,D] transposed test
  float* mem   = ws + o; o += (long)M_*B_*D_;     // memory
  float* wkMem = ws + o; o += (long)M_*B_*K_;     // l2n(memory@cw.T+cb)
  float* wq    = ws + o; o += (long)M_*B_*K_;     // enc wq / per-img wq
  float* big   = ws + o; o += (long)B_*M_*M_;     // enc scores; reused by decoder
  float* maskB = ws + o; o += HW_*B_;
  float* part  = ws + o; o += T_*B_*16;
  float* scaleG= ws + o; o += 64;
  float* wts   = ws + o; o += 4;

  // decoder sub-buffers inside `big` (30.6M <= 33.7M floats)
  float* scoresC = big;                               // [B,HW,M]
  float* scoresS = scoresC + (long)B_*HW_*M_;         // [B,HW,HW]
  float* W2      = scoresS + (long)B_*HW_*HW_;        // [B,HW,HW]
  float* tgt     = W2      + (long)B_*HW_*HW_;        // [HW,B,D]
  float* Xbuf    = tgt     + (long)HW_*B_*D_;         // [HW,B,D]
  float* outImg  = Xbuf    + (long)HW_*B_*D_;         // [HW,B,D]

  // ---- input transposes + qxm softmax ----
  k_transpose_in<<<dim3(16,16,T_*B_),256,0,stream>>>(train_feat, srcT);
  k_transpose_in<<<dim3(16,16,T_*B_),256,0,stream>>>(test_feat,  tstT);
  k_wts<<<1,64,0,stream>>>(qxm, wts);

  // ---- encoder: memory = inorm(src + selfattn(src), T) ----
  k_proj_l2n<<<(M_*B_+31)/32,256,0,stream>>>(srcT, sw, sb, wq, M_*B_);
  k_scores<8><<<dim3((M_+127)/128,(M_+127)/128,B_),256,0,stream>>>(wq, wq, big, M_, M_);
  k_softmax<<<B_*M_,256,0,stream>>>(big, M_);
  k_av<8,true,false><<<dim3((M_+127)/128, D_/128, B_),256,0,stream>>>(
      big, srcT, srcT, nullptr, mem, M_, M_);
  k_ss_partial<false><<<dim3(T_*B_,16),256,0,stream>>>(mem, nullptr, part);
  k_ss_final<<<1,64,0,stream>>>(part, scaleG, T_*B_);
  k_inorm_apply<<<(int)(((long)M_*B_*D_/4 + 255)/256),256,0,stream>>>(
      mem, scaleG, (long)M_*B_*D_/4);
  // cross keys of memory (shared by all 6 images)
  k_proj_l2n<<<(M_*B_+31)/32,256,0,stream>>>(mem, cw, cb, wkMem, M_*B_);

  // ---- decoder: 3 train images then 3 test images ----
  for (int img = 0; img < 2*T_; img++) {
    const float* base = (img < T_) ? srcT + (long)img*HW_*B_*D_
                                   : tstT + (long)(img - T_)*HW_*B_*D_;
    float* outP = out + (long)img*B_*D_*HW_;   // enc block then dec block, contiguous

    // self-attention + inorm -> tgt
    k_proj_l2n<<<(HW_*B_+31)/32,256,0,stream>>>(base, sw, sb, wq, HW_*B_);
    k_scores<4><<<dim3((HW_+127)/128,(HW_+63)/64,B_),256,0,stream>>>(
        wq, wq, scoresS, HW_, HW_);
    k_softmax<<<B_*HW_,256,0,stream>>>(scoresS, HW_);
    k_av<4,true,false><<<dim3((HW_+127)/128, D_/64, B_),256,0,stream>>>(
        scoresS, base, base, nullptr, tgt, HW_, HW_);
    k_ss_partial<false><<<dim3(B_,16),256,0,stream>>>(tgt, nullptr, part);
    k_ss_final<<<1,64,0,stream>>>(part, scaleG, B_);
    k_inorm_apply<<<(int)(((long)HW_*B_*D_/4 + 255)/256),256,0,stream>>>(
        tgt, scaleG, (long)HW_*B_*D_/4);

    // shared cross-attention weights aff = softmax(30*wq(tgt)·wk(memory))
    k_proj_l2n<<<(HW_*B_+31)/32,256,0,stream>>>(tgt, cw, cb, wq, HW_*B_);
    k_scores<4><<<dim3((HW_+127)/128,(M_+63)/64,B_),256,0,stream>>>(
        wq, wkMem, scoresC, HW_, M_);
    k_softmax<<<B_*HW_,256,0,stream>>>(scoresC, M_);

    // W2 (label-weighted fold of aff) and mask (= row-sum of W2)
    k_w2<<<(int)(((long)B_*HW_*HW_ + 255)/256),256,0,stream>>>(scoresC, label, W2);
    k_mask<<<B_*HW_,256,0,stream>>>(W2, maskB);

    // t_base = inorm(tgt*mask):  out = w0*scale*tgt*mask
    k_ss_partial<true><<<dim3(B_,16),256,0,stream>>>(tgt, maskB, part);
    k_ss_final<<<1,64,0,stream>>>(part, scaleG, B_);
    k_accum<0><<<(int)(((long)HW_*B_*D_/4 + 255)/256),256,0,stream>>>(
        tgt, maskB, scaleG, wts, outImg, 0);

    // t_q = inorm(W2@tgt + tgt):  out += w1*scale*X
    k_av<4,true,false><<<dim3((HW_+127)/128, D_/64, B_),256,0,stream>>>(
        W2, tgt, tgt, nullptr, Xbuf, HW_, HW_);
    k_ss_partial<false><<<dim3(B_,16),256,0,stream>>>(Xbuf, nullptr, part);
    k_ss_final<<<1,64,0,stream>>>(part, scaleG, B_);
    k_accum<1><<<(int)(((long)HW_*B_*D_/4 + 255)/256),256,0,stream>>>(
        Xbuf, nullptr, scaleG, wts, outImg, 1);

    // t_v = inorm((aff*pos1)@memory + tgt):  out += w2*scale*X
    k_av<4,true,true><<<dim3((HW_+127)/128, D_/64, B_),256,0,stream>>>(
        scoresC, mem, tgt, label, Xbuf, HW_, M_);
    k_ss_partial<false><<<dim3(B_,16),256,0,stream>>>(Xbuf, nullptr, part);
    k_ss_final<<<1,64,0,stream>>>(part, scaleG, B_);
    k_accum<1><<<(int)(((long)HW_*B_*D_/4 + 255)/256),256,0,stream>>>(
        Xbuf, nullptr, scaleG, wts, outImg, 2);

    k_out_store<<<dim3(16,16,B_),256,0,stream>>>(outImg, outP);
  }
}